// Round 2
// baseline (168.035 us; speedup 1.0000x reference)
//
#include <hip/hip_runtime.h>

#define NN 512   // N
// D = 16 floats = 4 float4 per message

typedef float f4 __attribute__((ext_vector_type(4)));

// Position of the k-th (0-indexed) set bit of m. Assumes k < popcll(m).
__device__ __forceinline__ int select_bit(unsigned long long m, int k) {
    int pos = 0;
    unsigned int w = (unsigned int)m;
    int c = __popc(w);
    if (k >= c) { k -= c; pos = 32; w = (unsigned int)(m >> 32); }
    unsigned int h = w & 0xFFFFu; c = __popc(h);
    if (k >= c) { k -= c; pos += 16; w >>= 16; }
    h = w & 0xFFu; c = __popc(h);
    if (k >= c) { k -= c; pos += 8; w >>= 8; }
    h = w & 0xFu; c = __popc(h);
    if (k >= c) { k -= c; pos += 4; w >>= 4; }
    h = w & 0x3u; c = __popc(h);
    if (k >= c) { k -= c; pos += 2; w >>= 2; }
    if (k >= (int)(w & 0x1u)) pos += 1;
    return pos;
}

// One block per (b, i) output row. 512 threads, zero LDS, zero barriers.
// Compaction (position -> source column) computed in registers from 8
// wave-wide ballots over the adj row (each wave redundantly loads the same
// 2 KiB row -> L1 hits). Output written as nontemporal float4 streams.
__global__ __launch_bounds__(512) void graph_layer_kernel(
    const int*   __restrict__ adj,    // [B][N][N] int32
    const float* __restrict__ coef,   // [B][N][N] fp32
    const f4*    __restrict__ msg4,   // [B][N][4]  (= [B][N][16] fp32)
    f4*          __restrict__ out4)   // [B][N][N*4]
{
    const int row  = blockIdx.x;       // b*N + i
    const int b    = row >> 9;
    const int i    = row & (NN - 1);
    const int t    = threadIdx.x;
    const int lane = t & 63;
    const size_t rowbase = (size_t)row * NN;

    // 8 chunk masks of the adj row; every wave computes all 8 identically.
    unsigned long long mask[8];
    #pragma unroll
    for (int c = 0; c < 8; ++c)
        mask[c] = __ballot(adj[rowbase + c * 64 + lane] != -1);

    int cum[9];
    cum[0] = 0;
    #pragma unroll
    for (int c = 0; c < 8; ++c) cum[c + 1] = cum[c] + __popcll(mask[c]);

    const f4* msgb = msg4 + (size_t)b * (NN * 4);
    f4*       orow = out4 + (size_t)row * (NN * 4);
    const int q = t & 3;               // which float4 of the D=16 message

    #pragma unroll
    for (int k = 0; k < 4; ++k) {
        const int g = t + k * 512;     // float4 index within the output row
        const int j = g >> 2;          // output column (neighbor slot)

        int s;                         // source message row
        if (j == 0) {
            s = i;                     // self message first
        } else {
            const int p = j - 1;       // compacted position
            if (p >= cum[8]) {
                s = NN - 1;            // fill value n, JAX-clamped to n-1
            } else {
                int c = 0;
                #pragma unroll
                for (int cc = 1; cc < 8; ++cc) c += (p >= cum[cc]) ? 1 : 0;
                s = c * 64 + select_bit(mask[c], p - cum[c]);
            }
        }

        const float cv = coef[rowbase + j];   // 4-lane broadcast, one L1 line/wave
        const f4    v  = msgb[s * 4 + q];     // mostly contiguous, L1/L2-resident
        f4 o;
        o.x = cv * v.x; o.y = cv * v.y; o.z = cv * v.z; o.w = cv * v.w;
        __builtin_nontemporal_store(o, orow + g);
    }
}

extern "C" void kernel_launch(void* const* d_in, const int* in_sizes, int n_in,
                              void* d_out, int out_size, void* d_ws, size_t ws_size,
                              hipStream_t stream) {
    const int*   adj  = (const int*)d_in[0];    // adj_matrix (int32)
    const float* coef = (const float*)d_in[1];  // adj_coef
    const f4*    msg4 = (const f4*)d_in[2];     // neighbour_messages
    f4*          out4 = (f4*)d_out;             // fp32 output

    const int B = 8;
    graph_layer_kernel<<<B * NN, 512, 0, stream>>>(adj, coef, msg4, out4);
}

// Round 3
// 167.495 us; speedup vs baseline: 1.0032x; 1.0032x over previous
//
#include <hip/hip_runtime.h>

#define NN 512   // N
// D = 16 floats = 4 float4 per message

typedef float f4 __attribute__((ext_vector_type(4)));

// ---------------------------------------------------------------------------
// Kernel 1: compaction. For each row (b,i), build the position -> source-row
// map: sidx[row][0] = i (self), sidx[row][1+p] = p-th valid column,
// sidx[row][t>V] = NN-1 (JAX fill index n clamped to n-1).
// Each of the 512 slots is written by exactly ONE thread -> no race, and the
// only barrier is for the cross-wave count exchange.
// ---------------------------------------------------------------------------
__global__ __launch_bounds__(512) void compact_kernel(
    const int* __restrict__ adj,    // [B][N][N] int32
    int*       __restrict__ sidx)   // [B*N][N]
{
    __shared__ int wtot[8];
    const int row  = blockIdx.x;         // b*N + i
    const int i    = row & (NN - 1);
    const int t    = threadIdx.x;
    const int lane = t & 63;
    const int wv   = t >> 6;

    const bool valid = (adj[(size_t)row * NN + t] != -1);
    const unsigned long long m = __ballot(valid);
    const int rank = __popcll(m & ((1ULL << lane) - 1ULL));
    if (lane == 0) wtot[wv] = __popcll(m);
    __syncthreads();

    int base = 0, V = 0;
    #pragma unroll
    for (int w = 0; w < 8; ++w) {
        base += (w < wv) ? wtot[w] : 0;
        V += wtot[w];
    }

    int* srow = sidx + (size_t)row * NN;
    if (t == 0) srow[0] = i;                       // self message first
    if (valid) {
        const int pos = 1 + base + rank;
        if (pos < NN) srow[pos] = t;
    }
    if (t > V) srow[t] = NN - 1;                   // fill (clamped gather)
}

// ---------------------------------------------------------------------------
// Kernel 2: pure streaming write. No LDS, no barriers, no ballots.
// One block per (b,i) row; 512 threads x 4 float4 each = 2048 f4 = 32 KiB row.
// ---------------------------------------------------------------------------
__global__ __launch_bounds__(512) void write_kernel(
    const int*   __restrict__ sidx,   // [B*N][N]
    const float* __restrict__ coef,   // [B][N][N] fp32
    const f4*    __restrict__ msg4,   // [B][N][4]
    f4*          __restrict__ out4)   // [B][N][N*4]
{
    const int row = blockIdx.x;        // b*N + i
    const int b   = row >> 9;
    const int t   = threadIdx.x;
    const size_t rowbase = (size_t)row * NN;

    const int*   srow = sidx + rowbase;
    const float* crow = coef + rowbase;
    const f4*    msgb = msg4 + (size_t)b * (NN * 4);
    f4*          orow = out4 + (size_t)row * (NN * 4);
    const int q = t & 3;               // which float4 of the D=16 message

    #pragma unroll
    for (int k = 0; k < 4; ++k) {
        const int g = t + k * 512;     // float4 index within the output row
        const int j = g >> 2;          // output column (neighbor slot)
        const int s = srow[j];         // source message row (L1, 4-lane bcast)
        const float c = crow[j];       // one L1 line per wave
        const f4    v = msgb[s * 4 + q];
        f4 o;
        o.x = c * v.x; o.y = c * v.y; o.z = c * v.z; o.w = c * v.w;
        __builtin_nontemporal_store(o, orow + g);
    }
}

extern "C" void kernel_launch(void* const* d_in, const int* in_sizes, int n_in,
                              void* d_out, int out_size, void* d_ws, size_t ws_size,
                              hipStream_t stream) {
    const int*   adj  = (const int*)d_in[0];    // adj_matrix (int32)
    const float* coef = (const float*)d_in[1];  // adj_coef
    const f4*    msg4 = (const f4*)d_in[2];     // neighbour_messages
    f4*          out4 = (f4*)d_out;             // fp32 output
    int*         sidx = (int*)d_ws;             // 8 MB scratch: [4096][512] int32

    const int B = 8;
    compact_kernel<<<B * NN, 512, 0, stream>>>(adj, sidx);
    write_kernel  <<<B * NN, 512, 0, stream>>>(sidx, coef, msg4, out4);
}